// Round 1
// baseline (12648.122 us; speedup 1.0000x reference)
//
#include <hip/hip_runtime.h>
#include <hip/hip_bf16.h>
#include <math.h>

#define N_NODES_C 50000
#define N_EDGES_C 800000
#define DIM 512
#define NUM_GRAPHS_C 64
#define NUM_CLASSES_C 10

#define BM 64
#define BN 64
#define BK 16

// ---------------- small prep kernels ----------------

__global__ void k_deg(const int* __restrict__ src, float* __restrict__ deg) {
    int e = blockIdx.x * blockDim.x + threadIdx.x;
    if (e < N_EDGES_C) {
        int s = src[e];
        if ((unsigned)s < N_NODES_C) atomicAdd(&deg[s], 1.0f);
    }
}

__global__ void k_cnt(const int* __restrict__ batch, int* __restrict__ cnt) {
    int n = blockIdx.x * blockDim.x + threadIdx.x;
    if (n < N_NODES_C) {
        int g = batch[n];
        if ((unsigned)g < NUM_GRAPHS_C) atomicAdd(&cnt[g], 1);
    }
}

// Weff[d,j] = sum_k sign[k,d] * Wp[k*128+col[k,d], j]
// Hm layout: [4][512][128], exactly one nonzero (+-1) per (k,d) row.
__global__ void k_weff(const float* __restrict__ Hm, const float* __restrict__ Wp,
                       float* __restrict__ Weff) {
    __shared__ int   scol[4];
    __shared__ float ssign[4];
    int d = blockIdx.x;
    int h = threadIdx.x;  // 128 threads
    for (int k = 0; k < 4; ++k) {
        float v = Hm[((size_t)k * DIM + d) * 128 + h];
        if (v != 0.0f) { scol[k] = h; ssign[k] = v; }
    }
    __syncthreads();
    for (int j = threadIdx.x; j < DIM; j += 128) {
        float acc = 0.0f;
#pragma unroll
        for (int k = 0; k < 4; ++k)
            acc += ssign[k] * Wp[(size_t)(k * 128 + scol[k]) * DIM + j];
        Weff[(size_t)d * DIM + j] = acc;
    }
}

// ---------------- aggregation ----------------

// nsum[src[e]] += H[dst[e]] ; 2 edges per 256-thread block, 128 lanes/edge, float4.
__global__ void k_scatter(const float* __restrict__ H, const int* __restrict__ src,
                          const int* __restrict__ dst, float* __restrict__ nsum) {
    int e = blockIdx.x * 2 + (threadIdx.x >> 7);
    int lane = threadIdx.x & 127;
    if (e >= N_EDGES_C) return;
    int s = src[e], d = dst[e];
    if ((unsigned)s >= N_NODES_C || (unsigned)d >= N_NODES_C) return;
    float4 v = *(const float4*)(H + (size_t)d * DIM + lane * 4);
    float* p = nsum + (size_t)s * DIM + lane * 4;
    atomicAdd(p + 0, v.x);
    atomicAdd(p + 1, v.y);
    atomicAdd(p + 2, v.z);
    atomicAdd(p + 3, v.w);
}

// in-place: agg[n] = deg[n]>0 ? nsum[n]/deg[n] : fb[n]
__global__ void k_combine(float* __restrict__ nsum, const float* __restrict__ fb,
                          const float* __restrict__ deg) {
    int idx = blockIdx.x * blockDim.x + threadIdx.x;  // over N_NODES*128 float4s
    if (idx >= N_NODES_C * 128) return;
    int n  = idx >> 7;
    int c4 = (idx & 127) * 4;
    float dg = deg[n];
    float4 o;
    if (dg > 0.0f) {
        float4 v = *(const float4*)(nsum + (size_t)n * DIM + c4);
        float inv = 1.0f / dg;
        o = make_float4(v.x * inv, v.y * inv, v.z * inv, v.w * inv);
    } else {
        o = *(const float4*)(fb + (size_t)n * DIM + c4);
    }
    *(float4*)(nsum + (size_t)n * DIM + c4) = o;
}

// ---------------- dual-GEMM: C = ELU(A1@W1 + A2@W2 + b) ----------------
// 64x64 tile, BK=16, 256 threads, 4x4 micro-tile per thread.

__device__ __forceinline__ float eluf(float v) {
    return v > 0.0f ? v : expm1f(v);
}

__global__ __launch_bounds__(256)
void k_gemm_elu(const float* __restrict__ A1, const float* __restrict__ W1,
                const float* __restrict__ A2, const float* __restrict__ W2,
                const float* __restrict__ bias, float* __restrict__ C) {
    __shared__ __align__(16) float As[BK * BM];
    __shared__ __align__(16) float Bs[BK * BN];
    const int tid = threadIdx.x;
    const int tr = tid >> 4, tc = tid & 15;
    const int row0 = blockIdx.y * BM, col0 = blockIdx.x * BN;
    float acc[4][4] = {};
    const int lm = tid >> 2, lk0 = (tid & 3) * 4;   // A tile load: row lm, k lk0..lk0+3
    const int lk = tid >> 4, lc0 = (tid & 15) * 4;  // W tile load: k lk, col lc0..lc0+3
    const bool aval = (row0 + lm) < N_NODES_C;
    for (int p = 0; p < 2; ++p) {
        const float* A = p ? A2 : A1;
        const float* W = p ? W2 : W1;
        const float* arow = A + (size_t)(row0 + lm) * DIM;
        for (int kt = 0; kt < DIM; kt += BK) {
            float4 av = make_float4(0.f, 0.f, 0.f, 0.f);
            if (aval) av = *(const float4*)(arow + kt + lk0);
            float4 wv = *(const float4*)(W + (size_t)(kt + lk) * DIM + col0 + lc0);
            __syncthreads();
            As[(lk0 + 0) * BM + lm] = av.x;
            As[(lk0 + 1) * BM + lm] = av.y;
            As[(lk0 + 2) * BM + lm] = av.z;
            As[(lk0 + 3) * BM + lm] = av.w;
            *(float4*)(Bs + lk * BN + lc0) = wv;
            __syncthreads();
#pragma unroll
            for (int kk = 0; kk < BK; ++kk) {
                const float4 a = *(const float4*)(As + kk * BM + tr * 4);
                const float4 b = *(const float4*)(Bs + kk * BN + tc * 4);
                const float avv[4] = {a.x, a.y, a.z, a.w};
                const float bvv[4] = {b.x, b.y, b.z, b.w};
#pragma unroll
                for (int i = 0; i < 4; ++i)
#pragma unroll
                    for (int j = 0; j < 4; ++j) acc[i][j] += avv[i] * bvv[j];
            }
        }
    }
#pragma unroll
    for (int i = 0; i < 4; ++i) {
        int row = row0 + tr * 4 + i;
        if (row >= N_NODES_C) break;
        float4 o;
        float* op = &o.x;
#pragma unroll
        for (int j = 0; j < 4; ++j) {
            int col = col0 + tc * 4 + j;
            op[j] = eluf(acc[i][j] + bias[col]);
        }
        *(float4*)(C + (size_t)row * DIM + col0 + tc * 4) = o;
    }
}

// Same GEMM, but epilogue pools ELU'd rows by graph id into gsum[64][512].
__global__ __launch_bounds__(256)
void k_gemm_pool(const float* __restrict__ A1, const float* __restrict__ W1,
                 const float* __restrict__ A2, const float* __restrict__ W2,
                 const float* __restrict__ bias, const int* __restrict__ batch,
                 float* __restrict__ gsum) {
    __shared__ __align__(16) float As[BK * BM];
    __shared__ __align__(16) float Bs[BK * BN];
    const int tid = threadIdx.x;
    const int tr = tid >> 4, tc = tid & 15;
    const int row0 = blockIdx.y * BM, col0 = blockIdx.x * BN;
    float acc[4][4] = {};
    const int lm = tid >> 2, lk0 = (tid & 3) * 4;
    const int lk = tid >> 4, lc0 = (tid & 15) * 4;
    const bool aval = (row0 + lm) < N_NODES_C;
    for (int p = 0; p < 2; ++p) {
        const float* A = p ? A2 : A1;
        const float* W = p ? W2 : W1;
        const float* arow = A + (size_t)(row0 + lm) * DIM;
        for (int kt = 0; kt < DIM; kt += BK) {
            float4 av = make_float4(0.f, 0.f, 0.f, 0.f);
            if (aval) av = *(const float4*)(arow + kt + lk0);
            float4 wv = *(const float4*)(W + (size_t)(kt + lk) * DIM + col0 + lc0);
            __syncthreads();
            As[(lk0 + 0) * BM + lm] = av.x;
            As[(lk0 + 1) * BM + lm] = av.y;
            As[(lk0 + 2) * BM + lm] = av.z;
            As[(lk0 + 3) * BM + lm] = av.w;
            *(float4*)(Bs + lk * BN + lc0) = wv;
            __syncthreads();
#pragma unroll
            for (int kk = 0; kk < BK; ++kk) {
                const float4 a = *(const float4*)(As + kk * BM + tr * 4);
                const float4 b = *(const float4*)(Bs + kk * BN + tc * 4);
                const float avv[4] = {a.x, a.y, a.z, a.w};
                const float bvv[4] = {b.x, b.y, b.z, b.w};
#pragma unroll
                for (int i = 0; i < 4; ++i)
#pragma unroll
                    for (int j = 0; j < 4; ++j) acc[i][j] += avv[i] * bvv[j];
            }
        }
    }
    // pooled epilogue: batch is sorted, run-reduce the thread's 4 rows per column
    int bi[4];
    bool rv[4];
#pragma unroll
    for (int i = 0; i < 4; ++i) {
        int row = row0 + tr * 4 + i;
        rv[i] = row < N_NODES_C;
        bi[i] = rv[i] ? batch[row] : -1;
    }
#pragma unroll
    for (int j = 0; j < 4; ++j) {
        int col = col0 + tc * 4 + j;
        float bj = bias[col];
        int curg = -1;
        float run = 0.0f;
#pragma unroll
        for (int i = 0; i < 4; ++i) {
            if (!rv[i]) break;
            float v = eluf(acc[i][j] + bj);
            if (bi[i] != curg) {
                if ((unsigned)curg < NUM_GRAPHS_C)
                    atomicAdd(&gsum[(size_t)curg * DIM + col], run);
                curg = bi[i];
                run = 0.0f;
            }
            run += v;
        }
        if ((unsigned)curg < NUM_GRAPHS_C)
            atomicAdd(&gsum[(size_t)curg * DIM + col], run);
    }
}

// out[g,j] = (gsum[g,:]/max(cnt[g],1)) @ Wc[:,j] + bc[j]
__global__ void k_final(const float* __restrict__ gsum, const int* __restrict__ cnt,
                        const float* __restrict__ Wc, const float* __restrict__ bc,
                        float* __restrict__ out) {
    int g = blockIdx.x;
    int j = threadIdx.x;
    if (j >= NUM_CLASSES_C) return;
    float inv = 1.0f / (float)(cnt[g] > 1 ? cnt[g] : 1);
    float s = 0.0f;
    for (int c = 0; c < DIM; ++c) s += gsum[(size_t)g * DIM + c] * Wc[(size_t)c * NUM_CLASSES_C + j];
    out[g * NUM_CLASSES_C + j] = s * inv + bc[j];
}

// ---------------- launch ----------------

extern "C" void kernel_launch(void* const* d_in, const int* in_sizes, int n_in,
                              void* d_out, int out_size, void* d_ws, size_t ws_size,
                              hipStream_t stream) {
    const float* x   = (const float*)d_in[0];
    const int*   ei  = (const int*)d_in[1];
    const int*   src = ei;
    const int*   dst = ei + N_EDGES_C;
    const int* batch = (const int*)d_in[2];
    const float* Hm1 = (const float*)d_in[3];
    const float* Wp1 = (const float*)d_in[4];
    const float* Ws1 = (const float*)d_in[5];
    const float* b1  = (const float*)d_in[6];
    const float* Hm2 = (const float*)d_in[7];
    const float* Wp2 = (const float*)d_in[8];
    const float* Ws2 = (const float*)d_in[9];
    const float* b2  = (const float*)d_in[10];
    const float* Wc  = (const float*)d_in[11];
    const float* bc  = (const float*)d_in[12];
    float* out = (float*)d_out;

    char* ws = (char*)d_ws;
    size_t off = 0;
    auto alloc = [&](size_t bytes) {
        void* p = ws + off;
        off += (bytes + 255) & ~(size_t)255;
        return p;
    };
    const size_t nodeBytes = (size_t)N_NODES_C * DIM * sizeof(float);  // 102.4 MB
    float* bufA  = (float*)alloc(nodeBytes);            // nsum/agg
    float* bufB  = (float*)alloc(nodeBytes);            // h1
    float* Weff1 = (float*)alloc((size_t)DIM * DIM * 4);
    float* Weff2 = (float*)alloc((size_t)DIM * DIM * 4);
    float* deg   = (float*)alloc((size_t)N_NODES_C * 4);
    int*   cnt   = (int*)alloc((size_t)NUM_GRAPHS_C * 4);
    float* gsum  = (float*)alloc((size_t)NUM_GRAPHS_C * DIM * 4);

    hipMemsetAsync(deg, 0, (size_t)N_NODES_C * 4, stream);
    hipMemsetAsync(cnt, 0, (size_t)NUM_GRAPHS_C * 4, stream);
    hipMemsetAsync(gsum, 0, (size_t)NUM_GRAPHS_C * DIM * 4, stream);
    hipMemsetAsync(bufA, 0, nodeBytes, stream);

    k_deg<<<(N_EDGES_C + 255) / 256, 256, 0, stream>>>(src, deg);
    k_cnt<<<(N_NODES_C + 255) / 256, 256, 0, stream>>>(batch, cnt);
    k_weff<<<DIM, 128, 0, stream>>>(Hm1, Wp1, Weff1);
    k_weff<<<DIM, 128, 0, stream>>>(Hm2, Wp2, Weff2);

    dim3 gg(DIM / BN, (N_NODES_C + BM - 1) / BM);

    // layer 1
    k_scatter<<<(N_EDGES_C + 1) / 2, 256, 0, stream>>>(x, src, dst, bufA);
    k_combine<<<(N_NODES_C * 128 + 255) / 256, 256, 0, stream>>>(bufA, x, deg);
    k_gemm_elu<<<gg, 256, 0, stream>>>(bufA, Weff1, x, Ws1, b1, bufB);

    // layer 2
    hipMemsetAsync(bufA, 0, nodeBytes, stream);
    k_scatter<<<(N_EDGES_C + 1) / 2, 256, 0, stream>>>(bufB, src, dst, bufA);
    k_combine<<<(N_NODES_C * 128 + 255) / 256, 256, 0, stream>>>(bufA, bufB, deg);
    k_gemm_pool<<<gg, 256, 0, stream>>>(bufA, Weff2, bufB, Ws2, b2, batch, gsum);

    k_final<<<NUM_GRAPHS_C, 64, 0, stream>>>(gsum, cnt, Wc, bc, out);
}

// Round 2
// 2601.274 us; speedup vs baseline: 4.8623x; 4.8623x over previous
//
#include <hip/hip_runtime.h>
#include <hip/hip_bf16.h>
#include <math.h>

#define N_NODES_C 50000
#define N_EDGES_C 800000
#define DIM 512
#define NUM_GRAPHS_C 64
#define NUM_CLASSES_C 10

#define BM 64
#define BN 64
#define BK 16

// ---------------- CSR build ----------------

__global__ void k_hist(const int* __restrict__ src, int* __restrict__ cnt) {
    int e = blockIdx.x * blockDim.x + threadIdx.x;
    if (e < N_EDGES_C) atomicAdd(&cnt[src[e]], 1);
}

// single-block exclusive scan of cnt[0..n) -> start[0..n], start[n]=total
__global__ __launch_bounds__(1024)
void k_scan(const int* __restrict__ cnt, int* __restrict__ start,
            int* __restrict__ cursor, int n) {
    __shared__ int sh[1024];
    __shared__ int carry_s;
    if (threadIdx.x == 0) carry_s = 0;
    __syncthreads();
    for (int base = 0; base < n; base += 1024) {
        int i = base + threadIdx.x;
        int v = (i < n) ? cnt[i] : 0;
        sh[threadIdx.x] = v;
        __syncthreads();
        for (int ofs = 1; ofs < 1024; ofs <<= 1) {
            int t = (threadIdx.x >= (unsigned)ofs) ? sh[threadIdx.x - ofs] : 0;
            __syncthreads();
            sh[threadIdx.x] += t;
            __syncthreads();
        }
        int incl = sh[threadIdx.x];
        int carry = carry_s;
        if (i < n) {
            int ex = carry + incl - v;
            start[i] = ex;
            cursor[i] = ex;
        }
        __syncthreads();
        if (threadIdx.x == 1023) carry_s = carry + incl;
        __syncthreads();
    }
    if (threadIdx.x == 0) start[n] = carry_s;
}

__global__ void k_fill(const int* __restrict__ src, const int* __restrict__ dst,
                       int* __restrict__ cursor, int* __restrict__ ebuf) {
    int e = blockIdx.x * blockDim.x + threadIdx.x;
    if (e < N_EDGES_C) {
        int pos = atomicAdd(&cursor[src[e]], 1);
        ebuf[pos] = dst[e];
    }
}

__global__ void k_cnt(const int* __restrict__ batch, int* __restrict__ cnt) {
    int n = blockIdx.x * blockDim.x + threadIdx.x;
    if (n < N_NODES_C) {
        int g = batch[n];
        if ((unsigned)g < NUM_GRAPHS_C) atomicAdd(&cnt[g], 1);
    }
}

// Weff[d,j] = sum_k sign[k,d] * Wp[k*128+col[k,d], j]
__global__ void k_weff(const float* __restrict__ Hm, const float* __restrict__ Wp,
                       float* __restrict__ Weff) {
    __shared__ int   scol[4];
    __shared__ float ssign[4];
    int d = blockIdx.x;
    int h = threadIdx.x;  // 128 threads
    for (int k = 0; k < 4; ++k) {
        float v = Hm[((size_t)k * DIM + d) * 128 + h];
        if (v != 0.0f) { scol[k] = h; ssign[k] = v; }
    }
    __syncthreads();
    for (int j = threadIdx.x; j < DIM; j += 128) {
        float acc = 0.0f;
#pragma unroll
        for (int k = 0; k < 4; ++k)
            acc += ssign[k] * Wp[(size_t)(k * 128 + scol[k]) * DIM + j];
        Weff[(size_t)d * DIM + j] = acc;
    }
}

// ---------------- aggregation: CSR gather + mean/fallback fused ----------------
// one block (128 threads) per node; lane c covers columns 4c..4c+3.

__global__ __launch_bounds__(128)
void k_gather(const float* __restrict__ H, const int* __restrict__ start,
              const int* __restrict__ ebuf, const float* __restrict__ fb,
              float* __restrict__ out) {
    int n = blockIdx.x;
    int c4 = threadIdx.x * 4;
    int s = start[n], e = start[n + 1];
    float4 acc = make_float4(0.f, 0.f, 0.f, 0.f);
    int i = s;
    for (; i + 1 < e; i += 2) {
        int d0 = ebuf[i], d1 = ebuf[i + 1];
        float4 v0 = *(const float4*)(H + (size_t)d0 * DIM + c4);
        float4 v1 = *(const float4*)(H + (size_t)d1 * DIM + c4);
        acc.x += v0.x + v1.x; acc.y += v0.y + v1.y;
        acc.z += v0.z + v1.z; acc.w += v0.w + v1.w;
    }
    if (i < e) {
        int d0 = ebuf[i];
        float4 v0 = *(const float4*)(H + (size_t)d0 * DIM + c4);
        acc.x += v0.x; acc.y += v0.y; acc.z += v0.z; acc.w += v0.w;
    }
    float4 o;
    if (e > s) {
        float inv = 1.0f / (float)(e - s);
        o = make_float4(acc.x * inv, acc.y * inv, acc.z * inv, acc.w * inv);
    } else {
        o = *(const float4*)(fb + (size_t)n * DIM + c4);
    }
    *(float4*)(out + (size_t)n * DIM + c4) = o;
}

// ---------------- dual-GEMM: C = ELU(A1@W1 + A2@W2 + b) ----------------

__device__ __forceinline__ float eluf(float v) {
    return v > 0.0f ? v : expm1f(v);
}

__global__ __launch_bounds__(256)
void k_gemm_elu(const float* __restrict__ A1, const float* __restrict__ W1,
                const float* __restrict__ A2, const float* __restrict__ W2,
                const float* __restrict__ bias, float* __restrict__ C) {
    __shared__ __align__(16) float As[BK * BM];
    __shared__ __align__(16) float Bs[BK * BN];
    const int tid = threadIdx.x;
    const int tr = tid >> 4, tc = tid & 15;
    const int row0 = blockIdx.y * BM, col0 = blockIdx.x * BN;
    float acc[4][4] = {};
    const int lm = tid >> 2, lk0 = (tid & 3) * 4;
    const int lk = tid >> 4, lc0 = (tid & 15) * 4;
    const bool aval = (row0 + lm) < N_NODES_C;
    for (int p = 0; p < 2; ++p) {
        const float* A = p ? A2 : A1;
        const float* W = p ? W2 : W1;
        const float* arow = A + (size_t)(row0 + lm) * DIM;
        for (int kt = 0; kt < DIM; kt += BK) {
            float4 av = make_float4(0.f, 0.f, 0.f, 0.f);
            if (aval) av = *(const float4*)(arow + kt + lk0);
            float4 wv = *(const float4*)(W + (size_t)(kt + lk) * DIM + col0 + lc0);
            __syncthreads();
            As[(lk0 + 0) * BM + lm] = av.x;
            As[(lk0 + 1) * BM + lm] = av.y;
            As[(lk0 + 2) * BM + lm] = av.z;
            As[(lk0 + 3) * BM + lm] = av.w;
            *(float4*)(Bs + lk * BN + lc0) = wv;
            __syncthreads();
#pragma unroll
            for (int kk = 0; kk < BK; ++kk) {
                const float4 a = *(const float4*)(As + kk * BM + tr * 4);
                const float4 b = *(const float4*)(Bs + kk * BN + tc * 4);
                const float avv[4] = {a.x, a.y, a.z, a.w};
                const float bvv[4] = {b.x, b.y, b.z, b.w};
#pragma unroll
                for (int i = 0; i < 4; ++i)
#pragma unroll
                    for (int j = 0; j < 4; ++j) acc[i][j] += avv[i] * bvv[j];
            }
        }
    }
#pragma unroll
    for (int i = 0; i < 4; ++i) {
        int row = row0 + tr * 4 + i;
        if (row >= N_NODES_C) break;
        float4 o;
        float* op = &o.x;
#pragma unroll
        for (int j = 0; j < 4; ++j) {
            int col = col0 + tc * 4 + j;
            op[j] = eluf(acc[i][j] + bias[col]);
        }
        *(float4*)(C + (size_t)row * DIM + col0 + tc * 4) = o;
    }
}

// Same GEMM, epilogue pools ELU'd rows by (sorted) graph id into gsum[64][512].
__global__ __launch_bounds__(256)
void k_gemm_pool(const float* __restrict__ A1, const float* __restrict__ W1,
                 const float* __restrict__ A2, const float* __restrict__ W2,
                 const float* __restrict__ bias, const int* __restrict__ batch,
                 float* __restrict__ gsum) {
    __shared__ __align__(16) float As[BK * BM];
    __shared__ __align__(16) float Bs[BK * BN];
    const int tid = threadIdx.x;
    const int tr = tid >> 4, tc = tid & 15;
    const int row0 = blockIdx.y * BM, col0 = blockIdx.x * BN;
    float acc[4][4] = {};
    const int lm = tid >> 2, lk0 = (tid & 3) * 4;
    const int lk = tid >> 4, lc0 = (tid & 15) * 4;
    const bool aval = (row0 + lm) < N_NODES_C;
    for (int p = 0; p < 2; ++p) {
        const float* A = p ? A2 : A1;
        const float* W = p ? W2 : W1;
        const float* arow = A + (size_t)(row0 + lm) * DIM;
        for (int kt = 0; kt < DIM; kt += BK) {
            float4 av = make_float4(0.f, 0.f, 0.f, 0.f);
            if (aval) av = *(const float4*)(arow + kt + lk0);
            float4 wv = *(const float4*)(W + (size_t)(kt + lk) * DIM + col0 + lc0);
            __syncthreads();
            As[(lk0 + 0) * BM + lm] = av.x;
            As[(lk0 + 1) * BM + lm] = av.y;
            As[(lk0 + 2) * BM + lm] = av.z;
            As[(lk0 + 3) * BM + lm] = av.w;
            *(float4*)(Bs + lk * BN + lc0) = wv;
            __syncthreads();
#pragma unroll
            for (int kk = 0; kk < BK; ++kk) {
                const float4 a = *(const float4*)(As + kk * BM + tr * 4);
                const float4 b = *(const float4*)(Bs + kk * BN + tc * 4);
                const float avv[4] = {a.x, a.y, a.z, a.w};
                const float bvv[4] = {b.x, b.y, b.z, b.w};
#pragma unroll
                for (int i = 0; i < 4; ++i)
#pragma unroll
                    for (int j = 0; j < 4; ++j) acc[i][j] += avv[i] * bvv[j];
            }
        }
    }
    int bi[4];
    bool rv[4];
#pragma unroll
    for (int i = 0; i < 4; ++i) {
        int row = row0 + tr * 4 + i;
        rv[i] = row < N_NODES_C;
        bi[i] = rv[i] ? batch[row] : -1;
    }
#pragma unroll
    for (int j = 0; j < 4; ++j) {
        int col = col0 + tc * 4 + j;
        float bj = bias[col];
        int curg = -1;
        float run = 0.0f;
#pragma unroll
        for (int i = 0; i < 4; ++i) {
            if (!rv[i]) break;
            float v = eluf(acc[i][j] + bj);
            if (bi[i] != curg) {
                if ((unsigned)curg < NUM_GRAPHS_C)
                    atomicAdd(&gsum[(size_t)curg * DIM + col], run);
                curg = bi[i];
                run = 0.0f;
            }
            run += v;
        }
        if ((unsigned)curg < NUM_GRAPHS_C)
            atomicAdd(&gsum[(size_t)curg * DIM + col], run);
    }
}

// out[g,j] = (gsum[g,:]/max(cnt[g],1)) @ Wc[:,j] + bc[j]
__global__ void k_final(const float* __restrict__ gsum, const int* __restrict__ cnt,
                        const float* __restrict__ Wc, const float* __restrict__ bc,
                        float* __restrict__ out) {
    int g = blockIdx.x;
    int j = threadIdx.x;
    if (j >= NUM_CLASSES_C) return;
    int c_ = cnt[g];
    float inv = 1.0f / (float)(c_ > 1 ? c_ : 1);
    float s = 0.0f;
    for (int c = 0; c < DIM; ++c) s += gsum[(size_t)g * DIM + c] * Wc[(size_t)c * NUM_CLASSES_C + j];
    out[g * NUM_CLASSES_C + j] = s * inv + bc[j];
}

// ---------------- launch ----------------

extern "C" void kernel_launch(void* const* d_in, const int* in_sizes, int n_in,
                              void* d_out, int out_size, void* d_ws, size_t ws_size,
                              hipStream_t stream) {
    const float* x   = (const float*)d_in[0];
    const int*   ei  = (const int*)d_in[1];
    const int*   src = ei;
    const int*   dst = ei + N_EDGES_C;
    const int* batch = (const int*)d_in[2];
    const float* Hm1 = (const float*)d_in[3];
    const float* Wp1 = (const float*)d_in[4];
    const float* Ws1 = (const float*)d_in[5];
    const float* b1  = (const float*)d_in[6];
    const float* Hm2 = (const float*)d_in[7];
    const float* Wp2 = (const float*)d_in[8];
    const float* Ws2 = (const float*)d_in[9];
    const float* b2  = (const float*)d_in[10];
    const float* Wc  = (const float*)d_in[11];
    const float* bc  = (const float*)d_in[12];
    float* out = (float*)d_out;

    char* ws = (char*)d_ws;
    size_t off = 0;
    auto alloc = [&](size_t bytes) {
        void* p = ws + off;
        off += (bytes + 255) & ~(size_t)255;
        return p;
    };
    const size_t nodeBytes = (size_t)N_NODES_C * DIM * sizeof(float);  // 102.4 MB
    float* bufA  = (float*)alloc(nodeBytes);                 // agg
    float* bufB  = (float*)alloc(nodeBytes);                 // h1
    float* Weff1 = (float*)alloc((size_t)DIM * DIM * 4);
    float* Weff2 = (float*)alloc((size_t)DIM * DIM * 4);
    int*   cnt_i = (int*)alloc((size_t)N_NODES_C * 4);
    int*   start = (int*)alloc((size_t)(N_NODES_C + 1) * 4);
    int*   cursor= (int*)alloc((size_t)N_NODES_C * 4);
    int*   ebuf  = (int*)alloc((size_t)N_EDGES_C * 4);
    int*   cnt   = (int*)alloc((size_t)NUM_GRAPHS_C * 4);
    float* gsum  = (float*)alloc((size_t)NUM_GRAPHS_C * DIM * 4);

    hipMemsetAsync(cnt_i, 0, (size_t)N_NODES_C * 4, stream);
    hipMemsetAsync(cnt, 0, (size_t)NUM_GRAPHS_C * 4, stream);
    hipMemsetAsync(gsum, 0, (size_t)NUM_GRAPHS_C * DIM * 4, stream);

    // CSR build
    k_hist<<<(N_EDGES_C + 255) / 256, 256, 0, stream>>>(src, cnt_i);
    k_scan<<<1, 1024, 0, stream>>>(cnt_i, start, cursor, N_NODES_C);
    k_fill<<<(N_EDGES_C + 255) / 256, 256, 0, stream>>>(src, dst, cursor, ebuf);

    k_cnt<<<(N_NODES_C + 255) / 256, 256, 0, stream>>>(batch, cnt);
    k_weff<<<DIM, 128, 0, stream>>>(Hm1, Wp1, Weff1);
    k_weff<<<DIM, 128, 0, stream>>>(Hm2, Wp2, Weff2);

    dim3 gg(DIM / BN, (N_NODES_C + BM - 1) / BM);

    // layer 1
    k_gather<<<N_NODES_C, 128, 0, stream>>>(x, start, ebuf, x, bufA);
    k_gemm_elu<<<gg, 256, 0, stream>>>(bufA, Weff1, x, Ws1, b1, bufB);

    // layer 2
    k_gather<<<N_NODES_C, 128, 0, stream>>>(bufB, start, ebuf, bufB, bufA);
    k_gemm_pool<<<gg, 256, 0, stream>>>(bufA, Weff2, bufB, Ws2, b2, batch, gsum);

    k_final<<<NUM_GRAPHS_C, 64, 0, stream>>>(gsum, cnt, Wc, bc, out);
}

// Round 3
// 1123.529 us; speedup vs baseline: 11.2575x; 2.3153x over previous
//
#include <hip/hip_runtime.h>
#include <hip/hip_bf16.h>
#include <math.h>

#define N_NODES_C 50000
#define N_EDGES_C 800000
#define DIM 512
#define NUM_GRAPHS_C 64
#define NUM_CLASSES_C 10

typedef short bf16x8 __attribute__((ext_vector_type(8)));
typedef float f32x4 __attribute__((ext_vector_type(4)));

__device__ __forceinline__ float bf2f(short s) {
    return __uint_as_float(((unsigned)(unsigned short)s) << 16);
}
__device__ __forceinline__ short f2bf(float f) {
    unsigned u = __float_as_uint(f);
    u += 0x7FFF + ((u >> 16) & 1);  // RNE
    return (short)(u >> 16);
}
__device__ __forceinline__ float eluf(float v) {
    return v > 0.0f ? v : expm1f(v);
}

// ---------------- CSR build ----------------

__global__ void k_hist(const int* __restrict__ src, int* __restrict__ cnt) {
    int e = blockIdx.x * blockDim.x + threadIdx.x;
    if (e < N_EDGES_C) atomicAdd(&cnt[src[e]], 1);
}

__global__ __launch_bounds__(1024)
void k_scan(const int* __restrict__ cnt, int* __restrict__ start,
            int* __restrict__ cursor, int n) {
    __shared__ int sh[1024];
    __shared__ int carry_s;
    if (threadIdx.x == 0) carry_s = 0;
    __syncthreads();
    for (int base = 0; base < n; base += 1024) {
        int i = base + threadIdx.x;
        int v = (i < n) ? cnt[i] : 0;
        sh[threadIdx.x] = v;
        __syncthreads();
        for (int ofs = 1; ofs < 1024; ofs <<= 1) {
            int t = (threadIdx.x >= (unsigned)ofs) ? sh[threadIdx.x - ofs] : 0;
            __syncthreads();
            sh[threadIdx.x] += t;
            __syncthreads();
        }
        int incl = sh[threadIdx.x];
        int carry = carry_s;
        if (i < n) {
            int ex = carry + incl - v;
            start[i] = ex;
            cursor[i] = ex;
        }
        __syncthreads();
        if (threadIdx.x == 1023) carry_s = carry + incl;
        __syncthreads();
    }
    if (threadIdx.x == 0) start[n] = carry_s;
}

__global__ void k_fill(const int* __restrict__ src, const int* __restrict__ dst,
                       int* __restrict__ cursor, int* __restrict__ ebuf) {
    int e = blockIdx.x * blockDim.x + threadIdx.x;
    if (e < N_EDGES_C) {
        int pos = atomicAdd(&cursor[src[e]], 1);
        ebuf[pos] = dst[e];
    }
}

__global__ void k_cnt(const int* __restrict__ batch, int* __restrict__ cnt) {
    int n = blockIdx.x * blockDim.x + threadIdx.x;
    if (n < N_NODES_C) {
        int g = batch[n];
        if ((unsigned)g < NUM_GRAPHS_C) atomicAdd(&cnt[g], 1);
    }
}

// Weff[d,j] = sum_k sign[k,d] * Wp[k*128+col[k,d], j]   (fp32)
__global__ void k_weff(const float* __restrict__ Hm, const float* __restrict__ Wp,
                       float* __restrict__ Weff) {
    __shared__ int   scol[4];
    __shared__ float ssign[4];
    int d = blockIdx.x;
    int h = threadIdx.x;  // 128 threads
    for (int k = 0; k < 4; ++k) {
        float v = Hm[((size_t)k * DIM + d) * 128 + h];
        if (v != 0.0f) { scol[k] = h; ssign[k] = v; }
    }
    __syncthreads();
    for (int j = threadIdx.x; j < DIM; j += 128) {
        float acc = 0.0f;
#pragma unroll
        for (int k = 0; k < 4; ++k)
            acc += ssign[k] * Wp[(size_t)(k * 128 + scol[k]) * DIM + j];
        Weff[(size_t)d * DIM + j] = acc;
    }
}

// Wt[n][k] bf16, k-contiguous: k<512 -> Weff[k][n], k>=512 -> Ws[k-512][n]
__global__ void k_prepw(const float* __restrict__ Weff, const float* __restrict__ Ws,
                        short* __restrict__ Wt) {
    int n = blockIdx.x;
    for (int k = threadIdx.x; k < 2 * DIM; k += 256) {
        float v = (k < DIM) ? Weff[(size_t)k * DIM + n] : Ws[(size_t)(k - DIM) * DIM + n];
        Wt[(size_t)n * (2 * DIM) + k] = f2bf(v);
    }
}

// fp32 -> bf16 cast, 8 elems/thread
__global__ void k_cast(const float* __restrict__ x, short* __restrict__ xb) {
    int idx = blockIdx.x * blockDim.x + threadIdx.x;
    if (idx >= N_NODES_C * DIM / 8) return;
    const float* p = x + (size_t)idx * 8;
    bf16x8 o;
#pragma unroll
    for (int j = 0; j < 8; ++j) o[j] = f2bf(p[j]);
    *(bf16x8*)( ((short*)xb) + (size_t)idx * 8 ) = o;
}

// ---------------- aggregation: CSR gather + mean/fallback (bf16) ----------------
// one wave per node; lane covers 8 consecutive bf16 (16 B).
__global__ __launch_bounds__(256)
void k_gather_b(const short* __restrict__ H, const int* __restrict__ start,
                const int* __restrict__ ebuf, const short* __restrict__ fb,
                short* __restrict__ outb) {
    int n = blockIdx.x * 4 + (threadIdx.x >> 6);
    int l = threadIdx.x & 63;
    if (n >= N_NODES_C) return;
    int s = start[n], e = start[n + 1];
    float acc[8] = {0, 0, 0, 0, 0, 0, 0, 0};
    int i = s;
    for (; i + 1 < e; i += 2) {
        int d0 = ebuf[i], d1 = ebuf[i + 1];
        bf16x8 v0 = *(const bf16x8*)(H + (size_t)d0 * DIM + l * 8);
        bf16x8 v1 = *(const bf16x8*)(H + (size_t)d1 * DIM + l * 8);
#pragma unroll
        for (int j = 0; j < 8; ++j) acc[j] += bf2f(v0[j]) + bf2f(v1[j]);
    }
    if (i < e) {
        int d0 = ebuf[i];
        bf16x8 v0 = *(const bf16x8*)(H + (size_t)d0 * DIM + l * 8);
#pragma unroll
        for (int j = 0; j < 8; ++j) acc[j] += bf2f(v0[j]);
    }
    bf16x8 o;
    if (e > s) {
        float inv = 1.0f / (float)(e - s);
#pragma unroll
        for (int j = 0; j < 8; ++j) o[j] = f2bf(acc[j] * inv);
    } else {
        o = *(const bf16x8*)(fb + (size_t)n * DIM + l * 8);
    }
    *(bf16x8*)(outb + (size_t)n * DIM + l * 8) = o;
}

// ---------------- MFMA dual-GEMM: C = ELU(A1@W1 + A2@W2 + b) ----------------
// 128x128 tile, BK=64, 256 thr = 4 waves (2x2), each wave 4x4 of 16x16x32 MFMA.
// LDS stride 72 elem (144 B) -> conflict-free-ish reads/writes.

#define LDK 72

__global__ __launch_bounds__(256)
void k_gemm_elu_mfma(const short* __restrict__ A1, const short* __restrict__ A2,
                     const short* __restrict__ Wt, const float* __restrict__ bias,
                     short* __restrict__ C) {
    __shared__ __align__(16) short As[128 * LDK];
    __shared__ __align__(16) short Bs[128 * LDK];
    const int tid = threadIdx.x;
    const int l = tid & 63, w = tid >> 6;
    const int wm = w >> 1, wn = w & 1;
    const int q = l >> 4, t16 = l & 15;
    const int row0 = blockIdx.y * 128, col0 = blockIdx.x * 128;
    const int srow = tid >> 3;          // 0..31
    const int sk = (tid & 7) * 8;       // 0..56
    f32x4 acc[4][4] = {};
    for (int p = 0; p < 2; ++p) {
        const short* A = p ? A2 : A1;
        for (int kt = 0; kt < DIM; kt += 64) {
            bf16x8 av[4], bv[4];
#pragma unroll
            for (int i = 0; i < 4; ++i) {
                int r = i * 32 + srow;
                int grow = row0 + r;
                if (grow < N_NODES_C)
                    av[i] = *(const bf16x8*)(A + (size_t)grow * DIM + kt + sk);
                else
                    av[i] = (bf16x8){0, 0, 0, 0, 0, 0, 0, 0};
                bv[i] = *(const bf16x8*)(Wt + (size_t)(col0 + r) * (2 * DIM) + p * DIM + kt + sk);
            }
            __syncthreads();
#pragma unroll
            for (int i = 0; i < 4; ++i) {
                int r = i * 32 + srow;
                *(bf16x8*)(As + r * LDK + sk) = av[i];
                *(bf16x8*)(Bs + r * LDK + sk) = bv[i];
            }
            __syncthreads();
#pragma unroll
            for (int kh = 0; kh < 2; ++kh) {
                const int kk = kh * 32 + q * 8;
                bf16x8 af[4], bfv[4];
#pragma unroll
                for (int mi = 0; mi < 4; ++mi)
                    af[mi] = *(const bf16x8*)(As + (wm * 64 + mi * 16 + t16) * LDK + kk);
#pragma unroll
                for (int ni = 0; ni < 4; ++ni)
                    bfv[ni] = *(const bf16x8*)(Bs + (wn * 64 + ni * 16 + t16) * LDK + kk);
#pragma unroll
                for (int mi = 0; mi < 4; ++mi)
#pragma unroll
                    for (int ni = 0; ni < 4; ++ni)
                        acc[mi][ni] = __builtin_amdgcn_mfma_f32_16x16x32_bf16(
                            af[mi], bfv[ni], acc[mi][ni], 0, 0, 0);
            }
        }
    }
#pragma unroll
    for (int mi = 0; mi < 4; ++mi) {
        int rbase = row0 + wm * 64 + mi * 16 + q * 4;
#pragma unroll
        for (int ni = 0; ni < 4; ++ni) {
            int col = col0 + wn * 64 + ni * 16 + t16;
            float bj = bias[col];
#pragma unroll
            for (int r = 0; r < 4; ++r) {
                int row = rbase + r;
                if (row < N_NODES_C)
                    C[(size_t)row * DIM + col] = f2bf(eluf(acc[mi][ni][r] + bj));
            }
        }
    }
}

// Same GEMM, epilogue pools ELU'd rows by (sorted) graph id into gsum[64][512] fp32.
__global__ __launch_bounds__(256)
void k_gemm_pool_mfma(const short* __restrict__ A1, const short* __restrict__ A2,
                      const short* __restrict__ Wt, const float* __restrict__ bias,
                      const int* __restrict__ batch, float* __restrict__ gsum) {
    __shared__ __align__(16) short As[128 * LDK];
    __shared__ __align__(16) short Bs[128 * LDK];
    __shared__ int sbatch[128];
    const int tid = threadIdx.x;
    const int l = tid & 63, w = tid >> 6;
    const int wm = w >> 1, wn = w & 1;
    const int q = l >> 4, t16 = l & 15;
    const int row0 = blockIdx.y * 128, col0 = blockIdx.x * 128;
    const int srow = tid >> 3;
    const int sk = (tid & 7) * 8;
    if (tid < 128) {
        int rw = row0 + tid;
        sbatch[tid] = (rw < N_NODES_C) ? batch[rw] : -1;
    }
    f32x4 acc[4][4] = {};
    for (int p = 0; p < 2; ++p) {
        const short* A = p ? A2 : A1;
        for (int kt = 0; kt < DIM; kt += 64) {
            bf16x8 av[4], bv[4];
#pragma unroll
            for (int i = 0; i < 4; ++i) {
                int r = i * 32 + srow;
                int grow = row0 + r;
                if (grow < N_NODES_C)
                    av[i] = *(const bf16x8*)(A + (size_t)grow * DIM + kt + sk);
                else
                    av[i] = (bf16x8){0, 0, 0, 0, 0, 0, 0, 0};
                bv[i] = *(const bf16x8*)(Wt + (size_t)(col0 + r) * (2 * DIM) + p * DIM + kt + sk);
            }
            __syncthreads();
#pragma unroll
            for (int i = 0; i < 4; ++i) {
                int r = i * 32 + srow;
                *(bf16x8*)(As + r * LDK + sk) = av[i];
                *(bf16x8*)(Bs + r * LDK + sk) = bv[i];
            }
            __syncthreads();
#pragma unroll
            for (int kh = 0; kh < 2; ++kh) {
                const int kk = kh * 32 + q * 8;
                bf16x8 af[4], bfv[4];
#pragma unroll
                for (int mi = 0; mi < 4; ++mi)
                    af[mi] = *(const bf16x8*)(As + (wm * 64 + mi * 16 + t16) * LDK + kk);
#pragma unroll
                for (int ni = 0; ni < 4; ++ni)
                    bfv[ni] = *(const bf16x8*)(Bs + (wn * 64 + ni * 16 + t16) * LDK + kk);
#pragma unroll
                for (int mi = 0; mi < 4; ++mi)
#pragma unroll
                    for (int ni = 0; ni < 4; ++ni)
                        acc[mi][ni] = __builtin_amdgcn_mfma_f32_16x16x32_bf16(
                            af[mi], bfv[ni], acc[mi][ni], 0, 0, 0);
            }
        }
    }
#pragma unroll
    for (int mi = 0; mi < 4; ++mi) {
        int rb = wm * 64 + mi * 16 + q * 4;  // local row base
#pragma unroll
        for (int ni = 0; ni < 4; ++ni) {
            int col = col0 + wn * 64 + ni * 16 + t16;
            float bj = bias[col];
            int curg = -1;
            float run = 0.0f;
#pragma unroll
            for (int r = 0; r < 4; ++r) {
                int g = sbatch[rb + r];
                if (g < 0) break;
                float v = eluf(acc[mi][ni][r] + bj);
                if (g != curg) {
                    if (curg >= 0) atomicAdd(&gsum[(size_t)curg * DIM + col], run);
                    curg = g;
                    run = 0.0f;
                }
                run += v;
            }
            if (curg >= 0) atomicAdd(&gsum[(size_t)curg * DIM + col], run);
        }
    }
}

// out[g,j] = (gsum[g,:]/max(cnt[g],1)) @ Wc[:,j] + bc[j]
__global__ void k_final(const float* __restrict__ gsum, const int* __restrict__ cnt,
                        const float* __restrict__ Wc, const float* __restrict__ bc,
                        float* __restrict__ out) {
    int g = blockIdx.x;
    int j = threadIdx.x;
    if (j >= NUM_CLASSES_C) return;
    int c_ = cnt[g];
    float inv = 1.0f / (float)(c_ > 1 ? c_ : 1);
    float s = 0.0f;
    for (int c = 0; c < DIM; ++c)
        s += gsum[(size_t)g * DIM + c] * Wc[(size_t)c * NUM_CLASSES_C + j];
    out[g * NUM_CLASSES_C + j] = s * inv + bc[j];
}

// ---------------- launch ----------------

extern "C" void kernel_launch(void* const* d_in, const int* in_sizes, int n_in,
                              void* d_out, int out_size, void* d_ws, size_t ws_size,
                              hipStream_t stream) {
    const float* x   = (const float*)d_in[0];
    const int*   ei  = (const int*)d_in[1];
    const int*   src = ei;
    const int*   dst = ei + N_EDGES_C;
    const int* batch = (const int*)d_in[2];
    const float* Hm1 = (const float*)d_in[3];
    const float* Wp1 = (const float*)d_in[4];
    const float* Ws1 = (const float*)d_in[5];
    const float* b1  = (const float*)d_in[6];
    const float* Hm2 = (const float*)d_in[7];
    const float* Wp2 = (const float*)d_in[8];
    const float* Ws2 = (const float*)d_in[9];
    const float* b2  = (const float*)d_in[10];
    const float* Wc  = (const float*)d_in[11];
    const float* bc  = (const float*)d_in[12];
    float* out = (float*)d_out;

    char* ws = (char*)d_ws;
    size_t off = 0;
    auto alloc = [&](size_t bytes) {
        void* p = ws + off;
        off += (bytes + 255) & ~(size_t)255;
        return p;
    };
    const size_t nodeB16 = (size_t)N_NODES_C * DIM * 2;  // 51.2 MB
    short* xb    = (short*)alloc(nodeB16);
    short* aggB  = (short*)alloc(nodeB16);
    short* hB    = (short*)alloc(nodeB16);
    float* Weff1 = (float*)alloc((size_t)DIM * DIM * 4);
    float* Weff2 = (float*)alloc((size_t)DIM * DIM * 4);
    short* Wt1   = (short*)alloc((size_t)DIM * 2 * DIM * 2);
    short* Wt2   = (short*)alloc((size_t)DIM * 2 * DIM * 2);
    int*   cnt_i = (int*)alloc((size_t)N_NODES_C * 4);
    int*   start = (int*)alloc((size_t)(N_NODES_C + 1) * 4);
    int*   cursor= (int*)alloc((size_t)N_NODES_C * 4);
    int*   ebuf  = (int*)alloc((size_t)N_EDGES_C * 4);
    int*   cnt   = (int*)alloc((size_t)NUM_GRAPHS_C * 4);
    float* gsum  = (float*)alloc((size_t)NUM_GRAPHS_C * DIM * 4);

    hipMemsetAsync(cnt_i, 0, (size_t)N_NODES_C * 4, stream);
    hipMemsetAsync(cnt, 0, (size_t)NUM_GRAPHS_C * 4, stream);
    hipMemsetAsync(gsum, 0, (size_t)NUM_GRAPHS_C * DIM * 4, stream);

    // CSR build + weight prep + casts
    k_hist<<<(N_EDGES_C + 255) / 256, 256, 0, stream>>>(src, cnt_i);
    k_scan<<<1, 1024, 0, stream>>>(cnt_i, start, cursor, N_NODES_C);
    k_fill<<<(N_EDGES_C + 255) / 256, 256, 0, stream>>>(src, dst, cursor, ebuf);
    k_cnt<<<(N_NODES_C + 255) / 256, 256, 0, stream>>>(batch, cnt);
    k_weff<<<DIM, 128, 0, stream>>>(Hm1, Wp1, Weff1);
    k_weff<<<DIM, 128, 0, stream>>>(Hm2, Wp2, Weff2);
    k_prepw<<<DIM, 256, 0, stream>>>(Weff1, Ws1, Wt1);
    k_prepw<<<DIM, 256, 0, stream>>>(Weff2, Ws2, Wt2);
    k_cast<<<(N_NODES_C * DIM / 8 + 255) / 256, 256, 0, stream>>>(x, xb);

    dim3 gg(DIM / 128, (N_NODES_C + 127) / 128);

    // layer 1
    k_gather_b<<<(N_NODES_C + 3) / 4, 256, 0, stream>>>(xb, start, ebuf, xb, aggB);
    k_gemm_elu_mfma<<<gg, 256, 0, stream>>>(aggB, xb, Wt1, b1, hB);

    // layer 2
    k_gather_b<<<(N_NODES_C + 3) / 4, 256, 0, stream>>>(hB, start, ebuf, hB, aggB);
    k_gemm_pool_mfma<<<gg, 256, 0, stream>>>(aggB, hB, Wt2, b2, batch, gsum);

    k_final<<<NUM_GRAPHS_C, 64, 0, stream>>>(gsum, cnt, Wc, bc, out);
}

// Round 4
// 892.469 us; speedup vs baseline: 14.1721x; 1.2589x over previous
//
#include <hip/hip_runtime.h>
#include <hip/hip_bf16.h>
#include <math.h>

#define N_NODES_C 50000
#define N_EDGES_C 800000
#define DIM 512
#define NUM_GRAPHS_C 64
#define NUM_CLASSES_C 10

typedef short bf16x8 __attribute__((ext_vector_type(8)));
typedef float f32x4 __attribute__((ext_vector_type(4)));

__device__ __forceinline__ float bf2f(short s) {
    return __uint_as_float(((unsigned)(unsigned short)s) << 16);
}
__device__ __forceinline__ short f2bf(float f) {
    unsigned u = __float_as_uint(f);
    u += 0x7FFF + ((u >> 16) & 1);  // RNE
    return (short)(u >> 16);
}
__device__ __forceinline__ float eluf(float v) {
    return v > 0.0f ? v : expm1f(v);
}

// ---------------- CSR build ----------------

__global__ void k_hist(const int* __restrict__ src, int* __restrict__ cnt) {
    int e = blockIdx.x * blockDim.x + threadIdx.x;
    if (e < N_EDGES_C) atomicAdd(&cnt[src[e]], 1);
}

__global__ __launch_bounds__(1024)
void k_scan(const int* __restrict__ cnt, int* __restrict__ start,
            int* __restrict__ cursor, int n) {
    __shared__ int sh[1024];
    __shared__ int carry_s;
    if (threadIdx.x == 0) carry_s = 0;
    __syncthreads();
    for (int base = 0; base < n; base += 1024) {
        int i = base + threadIdx.x;
        int v = (i < n) ? cnt[i] : 0;
        sh[threadIdx.x] = v;
        __syncthreads();
        for (int ofs = 1; ofs < 1024; ofs <<= 1) {
            int t = (threadIdx.x >= (unsigned)ofs) ? sh[threadIdx.x - ofs] : 0;
            __syncthreads();
            sh[threadIdx.x] += t;
            __syncthreads();
        }
        int incl = sh[threadIdx.x];
        int carry = carry_s;
        if (i < n) {
            int ex = carry + incl - v;
            start[i] = ex;
            cursor[i] = ex;
        }
        __syncthreads();
        if (threadIdx.x == 1023) carry_s = carry + incl;
        __syncthreads();
    }
    if (threadIdx.x == 0) start[n] = carry_s;
}

__global__ void k_fill(const int* __restrict__ src, const int* __restrict__ dst,
                       int* __restrict__ cursor, int* __restrict__ ebuf) {
    int e = blockIdx.x * blockDim.x + threadIdx.x;
    if (e < N_EDGES_C) {
        int pos = atomicAdd(&cursor[src[e]], 1);
        ebuf[pos] = dst[e];
    }
}

// per-block LDS histogram of batch -> cnt[64]; 50000 global atomics -> 64/block
__global__ __launch_bounds__(1024)
void k_cnt(const int* __restrict__ batch, int* __restrict__ cnt) {
    __shared__ int h[NUM_GRAPHS_C];
    if (threadIdx.x < NUM_GRAPHS_C) h[threadIdx.x] = 0;
    __syncthreads();
    int n = blockIdx.x * blockDim.x + threadIdx.x;
    if (n < N_NODES_C) {
        int g = batch[n];
        if ((unsigned)g < NUM_GRAPHS_C) atomicAdd(&h[g], 1);
    }
    __syncthreads();
    if (threadIdx.x < NUM_GRAPHS_C && h[threadIdx.x] > 0)
        atomicAdd(&cnt[threadIdx.x], h[threadIdx.x]);
}

// Weff[d,j] = sum_k sign[k,d] * Wp[k*128+col[k,d], j]   (fp32)
__global__ void k_weff(const float* __restrict__ Hm, const float* __restrict__ Wp,
                       float* __restrict__ Weff) {
    __shared__ int   scol[4];
    __shared__ float ssign[4];
    int d = blockIdx.x;
    int h = threadIdx.x;  // 128 threads
    for (int k = 0; k < 4; ++k) {
        float v = Hm[((size_t)k * DIM + d) * 128 + h];
        if (v != 0.0f) { scol[k] = h; ssign[k] = v; }
    }
    __syncthreads();
    for (int j = threadIdx.x; j < DIM; j += 128) {
        float acc = 0.0f;
#pragma unroll
        for (int k = 0; k < 4; ++k)
            acc += ssign[k] * Wp[(size_t)(k * 128 + scol[k]) * DIM + j];
        Weff[(size_t)d * DIM + j] = acc;
    }
}

// Wt[n][k] bf16, k-contiguous: k<512 -> Weff[k][n], k>=512 -> Ws[k-512][n]
__global__ void k_prepw(const float* __restrict__ Weff, const float* __restrict__ Ws,
                        short* __restrict__ Wt) {
    int n = blockIdx.x;
    for (int k = threadIdx.x; k < 2 * DIM; k += 256) {
        float v = (k < DIM) ? Weff[(size_t)k * DIM + n] : Ws[(size_t)(k - DIM) * DIM + n];
        Wt[(size_t)n * (2 * DIM) + k] = f2bf(v);
    }
}

// fp32 -> bf16 cast, 8 elems/thread
__global__ void k_cast(const float* __restrict__ x, short* __restrict__ xb) {
    int idx = blockIdx.x * blockDim.x + threadIdx.x;
    if (idx >= N_NODES_C * DIM / 8) return;
    const float* p = x + (size_t)idx * 8;
    bf16x8 o;
#pragma unroll
    for (int j = 0; j < 8; ++j) o[j] = f2bf(p[j]);
    *(bf16x8*)( ((short*)xb) + (size_t)idx * 8 ) = o;
}

// ---------------- aggregation: CSR gather + mean/fallback (bf16) ----------------
__global__ __launch_bounds__(256)
void k_gather_b(const short* __restrict__ H, const int* __restrict__ start,
                const int* __restrict__ ebuf, const short* __restrict__ fb,
                short* __restrict__ outb) {
    int n = blockIdx.x * 4 + (threadIdx.x >> 6);
    int l = threadIdx.x & 63;
    if (n >= N_NODES_C) return;
    int s = start[n], e = start[n + 1];
    float acc[8] = {0, 0, 0, 0, 0, 0, 0, 0};
    int i = s;
    for (; i + 1 < e; i += 2) {
        int d0 = ebuf[i], d1 = ebuf[i + 1];
        bf16x8 v0 = *(const bf16x8*)(H + (size_t)d0 * DIM + l * 8);
        bf16x8 v1 = *(const bf16x8*)(H + (size_t)d1 * DIM + l * 8);
#pragma unroll
        for (int j = 0; j < 8; ++j) acc[j] += bf2f(v0[j]) + bf2f(v1[j]);
    }
    if (i < e) {
        int d0 = ebuf[i];
        bf16x8 v0 = *(const bf16x8*)(H + (size_t)d0 * DIM + l * 8);
#pragma unroll
        for (int j = 0; j < 8; ++j) acc[j] += bf2f(v0[j]);
    }
    bf16x8 o;
    if (e > s) {
        float inv = 1.0f / (float)(e - s);
#pragma unroll
        for (int j = 0; j < 8; ++j) o[j] = f2bf(acc[j] * inv);
    } else {
        o = *(const bf16x8*)(fb + (size_t)n * DIM + l * 8);
    }
    *(bf16x8*)(outb + (size_t)n * DIM + l * 8) = o;
}

// ---------------- MFMA dual-GEMM: C = ELU(A1@W1 + A2@W2 + b) ----------------
#define LDK 72

__global__ __launch_bounds__(256)
void k_gemm_elu_mfma(const short* __restrict__ A1, const short* __restrict__ A2,
                     const short* __restrict__ Wt, const float* __restrict__ bias,
                     short* __restrict__ C) {
    __shared__ __align__(16) short As[128 * LDK];
    __shared__ __align__(16) short Bs[128 * LDK];
    const int tid = threadIdx.x;
    const int l = tid & 63, w = tid >> 6;
    const int wm = w >> 1, wn = w & 1;
    const int q = l >> 4, t16 = l & 15;
    const int row0 = blockIdx.y * 128, col0 = blockIdx.x * 128;
    const int srow = tid >> 3;          // 0..31
    const int sk = (tid & 7) * 8;       // 0..56
    f32x4 acc[4][4] = {};
    for (int p = 0; p < 2; ++p) {
        const short* A = p ? A2 : A1;
        for (int kt = 0; kt < DIM; kt += 64) {
            bf16x8 av[4], bv[4];
#pragma unroll
            for (int i = 0; i < 4; ++i) {
                int r = i * 32 + srow;
                int grow = row0 + r;
                if (grow < N_NODES_C)
                    av[i] = *(const bf16x8*)(A + (size_t)grow * DIM + kt + sk);
                else
                    av[i] = (bf16x8){0, 0, 0, 0, 0, 0, 0, 0};
                bv[i] = *(const bf16x8*)(Wt + (size_t)(col0 + r) * (2 * DIM) + p * DIM + kt + sk);
            }
            __syncthreads();
#pragma unroll
            for (int i = 0; i < 4; ++i) {
                int r = i * 32 + srow;
                *(bf16x8*)(As + r * LDK + sk) = av[i];
                *(bf16x8*)(Bs + r * LDK + sk) = bv[i];
            }
            __syncthreads();
#pragma unroll
            for (int kh = 0; kh < 2; ++kh) {
                const int kk = kh * 32 + q * 8;
                bf16x8 af[4], bfv[4];
#pragma unroll
                for (int mi = 0; mi < 4; ++mi)
                    af[mi] = *(const bf16x8*)(As + (wm * 64 + mi * 16 + t16) * LDK + kk);
#pragma unroll
                for (int ni = 0; ni < 4; ++ni)
                    bfv[ni] = *(const bf16x8*)(Bs + (wn * 64 + ni * 16 + t16) * LDK + kk);
#pragma unroll
                for (int mi = 0; mi < 4; ++mi)
#pragma unroll
                    for (int ni = 0; ni < 4; ++ni)
                        acc[mi][ni] = __builtin_amdgcn_mfma_f32_16x16x32_bf16(
                            af[mi], bfv[ni], acc[mi][ni], 0, 0, 0);
            }
        }
    }
#pragma unroll
    for (int mi = 0; mi < 4; ++mi) {
        int rbase = row0 + wm * 64 + mi * 16 + q * 4;
#pragma unroll
        for (int ni = 0; ni < 4; ++ni) {
            int col = col0 + wn * 64 + ni * 16 + t16;
            float bj = bias[col];
#pragma unroll
            for (int r = 0; r < 4; ++r) {
                int row = rbase + r;
                if (row < N_NODES_C)
                    C[(size_t)row * DIM + col] = f2bf(eluf(acc[mi][ni][r] + bj));
            }
        }
    }
}

// Same GEMM, epilogue pools ELU'd rows by (sorted) graph id into gsum[64][512] fp32.
__global__ __launch_bounds__(256)
void k_gemm_pool_mfma(const short* __restrict__ A1, const short* __restrict__ A2,
                      const short* __restrict__ Wt, const float* __restrict__ bias,
                      const int* __restrict__ batch, float* __restrict__ gsum) {
    __shared__ __align__(16) short As[128 * LDK];
    __shared__ __align__(16) short Bs[128 * LDK];
    __shared__ int sbatch[128];
    const int tid = threadIdx.x;
    const int l = tid & 63, w = tid >> 6;
    const int wm = w >> 1, wn = w & 1;
    const int q = l >> 4, t16 = l & 15;
    const int row0 = blockIdx.y * 128, col0 = blockIdx.x * 128;
    const int srow = tid >> 3;
    const int sk = (tid & 7) * 8;
    if (tid < 128) {
        int rw = row0 + tid;
        sbatch[tid] = (rw < N_NODES_C) ? batch[rw] : -1;
    }
    f32x4 acc[4][4] = {};
    for (int p = 0; p < 2; ++p) {
        const short* A = p ? A2 : A1;
        for (int kt = 0; kt < DIM; kt += 64) {
            bf16x8 av[4], bv[4];
#pragma unroll
            for (int i = 0; i < 4; ++i) {
                int r = i * 32 + srow;
                int grow = row0 + r;
                if (grow < N_NODES_C)
                    av[i] = *(const bf16x8*)(A + (size_t)grow * DIM + kt + sk);
                else
                    av[i] = (bf16x8){0, 0, 0, 0, 0, 0, 0, 0};
                bv[i] = *(const bf16x8*)(Wt + (size_t)(col0 + r) * (2 * DIM) + p * DIM + kt + sk);
            }
            __syncthreads();
#pragma unroll
            for (int i = 0; i < 4; ++i) {
                int r = i * 32 + srow;
                *(bf16x8*)(As + r * LDK + sk) = av[i];
                *(bf16x8*)(Bs + r * LDK + sk) = bv[i];
            }
            __syncthreads();
#pragma unroll
            for (int kh = 0; kh < 2; ++kh) {
                const int kk = kh * 32 + q * 8;
                bf16x8 af[4], bfv[4];
#pragma unroll
                for (int mi = 0; mi < 4; ++mi)
                    af[mi] = *(const bf16x8*)(As + (wm * 64 + mi * 16 + t16) * LDK + kk);
#pragma unroll
                for (int ni = 0; ni < 4; ++ni)
                    bfv[ni] = *(const bf16x8*)(Bs + (wn * 64 + ni * 16 + t16) * LDK + kk);
#pragma unroll
                for (int mi = 0; mi < 4; ++mi)
#pragma unroll
                    for (int ni = 0; ni < 4; ++ni)
                        acc[mi][ni] = __builtin_amdgcn_mfma_f32_16x16x32_bf16(
                            af[mi], bfv[ni], acc[mi][ni], 0, 0, 0);
            }
        }
    }
#pragma unroll
    for (int mi = 0; mi < 4; ++mi) {
        int rb = wm * 64 + mi * 16 + q * 4;  // local row base
#pragma unroll
        for (int ni = 0; ni < 4; ++ni) {
            int col = col0 + wn * 64 + ni * 16 + t16;
            float bj = bias[col];
            int curg = -1;
            float run = 0.0f;
#pragma unroll
            for (int r = 0; r < 4; ++r) {
                int g = sbatch[rb + r];
                if (g < 0) break;
                float v = eluf(acc[mi][ni][r] + bj);
                if (g != curg) {
                    if (curg >= 0) atomicAdd(&gsum[(size_t)curg * DIM + col], run);
                    curg = g;
                    run = 0.0f;
                }
                run += v;
            }
            if (curg >= 0) atomicAdd(&gsum[(size_t)curg * DIM + col], run);
        }
    }
}

// out[g,j] = (gsum[g,:]/max(cnt[g],1)) @ Wc[:,j] + bc[j]
__global__ void k_final(const float* __restrict__ gsum, const int* __restrict__ cnt,
                        const float* __restrict__ Wc, const float* __restrict__ bc,
                        float* __restrict__ out) {
    int g = blockIdx.x;
    int j = threadIdx.x;
    if (j >= NUM_CLASSES_C) return;
    int c_ = cnt[g];
    float inv = 1.0f / (float)(c_ > 1 ? c_ : 1);
    float s = 0.0f;
    for (int c = 0; c < DIM; ++c)
        s += gsum[(size_t)g * DIM + c] * Wc[(size_t)c * NUM_CLASSES_C + j];
    out[g * NUM_CLASSES_C + j] = s * inv + bc[j];
}

// ---------------- launch ----------------

extern "C" void kernel_launch(void* const* d_in, const int* in_sizes, int n_in,
                              void* d_out, int out_size, void* d_ws, size_t ws_size,
                              hipStream_t stream) {
    const float* x   = (const float*)d_in[0];
    const int*   ei  = (const int*)d_in[1];
    const int*   src = ei;
    const int*   dst = ei + N_EDGES_C;
    const int* batch = (const int*)d_in[2];
    const float* Hm1 = (const float*)d_in[3];
    const float* Wp1 = (const float*)d_in[4];
    const float* Ws1 = (const float*)d_in[5];
    const float* b1  = (const float*)d_in[6];
    const float* Hm2 = (const float*)d_in[7];
    const float* Wp2 = (const float*)d_in[8];
    const float* Ws2 = (const float*)d_in[9];
    const float* b2  = (const float*)d_in[10];
    const float* Wc  = (const float*)d_in[11];
    const float* bc  = (const float*)d_in[12];
    float* out = (float*)d_out;

    char* ws = (char*)d_ws;
    size_t off = 0;
    auto alloc = [&](size_t bytes) {
        void* p = ws + off;
        off += (bytes + 255) & ~(size_t)255;
        return p;
    };
    const size_t nodeB16 = (size_t)N_NODES_C * DIM * 2;  // 51.2 MB
    short* xb    = (short*)alloc(nodeB16);
    short* aggB  = (short*)alloc(nodeB16);
    short* hB    = (short*)alloc(nodeB16);
    float* Weff1 = (float*)alloc((size_t)DIM * DIM * 4);
    float* Weff2 = (float*)alloc((size_t)DIM * DIM * 4);
    short* Wt1   = (short*)alloc((size_t)DIM * 2 * DIM * 2);
    short* Wt2   = (short*)alloc((size_t)DIM * 2 * DIM * 2);
    int*   cnt_i = (int*)alloc((size_t)N_NODES_C * 4);
    int*   start = (int*)alloc((size_t)(N_NODES_C + 1) * 4);
    int*   cursor= (int*)alloc((size_t)N_NODES_C * 4);
    int*   ebuf  = (int*)alloc((size_t)N_EDGES_C * 4);
    int*   cnt   = (int*)alloc((size_t)NUM_GRAPHS_C * 4);
    float* gsum  = (float*)alloc((size_t)NUM_GRAPHS_C * DIM * 4);

    hipMemsetAsync(cnt_i, 0, (size_t)N_NODES_C * 4, stream);
    hipMemsetAsync(cnt, 0, (size_t)NUM_GRAPHS_C * 4, stream);
    hipMemsetAsync(gsum, 0, (size_t)NUM_GRAPHS_C * DIM * 4, stream);

    // CSR build + weight prep + casts
    k_hist<<<(N_EDGES_C + 255) / 256, 256, 0, stream>>>(src, cnt_i);
    k_scan<<<1, 1024, 0, stream>>>(cnt_i, start, cursor, N_NODES_C);
    k_fill<<<(N_EDGES_C + 255) / 256, 256, 0, stream>>>(src, dst, cursor, ebuf);
    k_cnt<<<(N_NODES_C + 1023) / 1024, 1024, 0, stream>>>(batch, cnt);
    k_weff<<<DIM, 128, 0, stream>>>(Hm1, Wp1, Weff1);
    k_weff<<<DIM, 128, 0, stream>>>(Hm2, Wp2, Weff2);
    k_prepw<<<DIM, 256, 0, stream>>>(Weff1, Ws1, Wt1);
    k_prepw<<<DIM, 256, 0, stream>>>(Weff2, Ws2, Wt2);
    k_cast<<<(N_NODES_C * DIM / 8 + 255) / 256, 256, 0, stream>>>(x, xb);

    dim3 gg(DIM / 128, (N_NODES_C + 127) / 128);

    // layer 1
    k_gather_b<<<(N_NODES_C + 3) / 4, 256, 0, stream>>>(xb, start, ebuf, xb, aggB);
    k_gemm_elu_mfma<<<gg, 256, 0, stream>>>(aggB, xb, Wt1, b1, hB);

    // layer 2
    k_gather_b<<<(N_NODES_C + 3) / 4, 256, 0, stream>>>(hB, start, ebuf, hB, aggB);
    k_gemm_pool_mfma<<<gg, 256, 0, stream>>>(aggB, hB, Wt2, b2, batch, gsum);

    k_final<<<NUM_GRAPHS_C, 64, 0, stream>>>(gsum, cnt, Wc, bc, out);
}